// Round 5
// baseline (746.323 us; speedup 1.0000x reference)
//
#include <hip/hip_runtime.h>

// EdgeNorm, round 9: node-sorted edge ids + wave-per-node register reduction.
//
// Round-8 post-mortem: per-edge stats time is INVARIANT across random-gather
// (r5: 302us, 65% occ) and streaming (r8: 2x186us, 12% occ) versions. The
// invariant is the 17 LDS atomicAdds/edge. Implied cost ~3.4-4.2 cyc per
// scattered LDS atomic lane-op => floor ~310us for 3.2M x 17 - exactly what
// we measure. VALUBusy 0.4%, bank-conflict 0: the LDS atomic pipe is the
// wall and is invisible to both counters.
//
// Fix: zero per-edge LDS atomics. Sort edge IDS by node (global-atomic
// count -> 3-kernel scan -> atomic-claim scatter of u32 ids), then one WAVE
// per node: load its ~32 edge ids (contiguous u32), gather 32B/edge from
// scores (102MB, L3-resident), butterfly-reduce 8x(sum,sumsq) in registers,
// compute gain/bias coeffs inline, write AB (64B). coeff kernel + partials
// deleted. ws ~21MB (<< 75MB proven floor).
//
// Pipeline:
//   1. zero       : nodeCnt = 0
//   2. count_node : global atomicAdd per edge -> nodeCnt[100k]
//   3. nscan1/2/3 : exclusive prefix -> nodeStart, nodeCur (copy)
//   4. scatter    : q = atomicAdd(nodeCur[d]); eid[q] = e
//   5. node_stats : wave per node -> register reduce -> AB[node]=[A(8)|B(8)]
//   6. edge_out   : out = A[dst]*x + B[dst]

#define NHEADS  8
#define NNODES  100000
#define SCAN_B  1024                    // elements per scan block (256 thr x 4)
#define NS1B    ((NNODES + SCAN_B - 1) / SCAN_B)   // 98

__global__ __launch_bounds__(256)
void zero_kernel(unsigned* __restrict__ p, int n) {
    int i = blockIdx.x * 256 + threadIdx.x;
    if (i < n) p[i] = 0u;
}

__global__ __launch_bounds__(256)
void count_node_kernel(const int* __restrict__ dst,
                       unsigned* __restrict__ cnt, int E) {
    const int stride = (int)gridDim.x * 256 * 4;
    for (int i = ((int)blockIdx.x * 256 + (int)threadIdx.x) * 4; i < E; i += stride) {
        if (i + 4 <= E) {
            int4 d = *reinterpret_cast<const int4*>(dst + i);
            atomicAdd(&cnt[d.x], 1u);
            atomicAdd(&cnt[d.y], 1u);
            atomicAdd(&cnt[d.z], 1u);
            atomicAdd(&cnt[d.w], 1u);
        } else {
            for (int j = i; j < E; ++j) atomicAdd(&cnt[dst[j]], 1u);
        }
    }
}

// Scan level 1: per-1024-chunk exclusive scan + chunk totals.
__global__ __launch_bounds__(256)
void nscan1_kernel(const unsigned* __restrict__ cnt,
                   unsigned* __restrict__ part,
                   unsigned* __restrict__ bsum, int N) {
    __shared__ unsigned sc[256];
    const int base = (int)blockIdx.x * SCAN_B + (int)threadIdx.x * 4;
    unsigned c0 = (base + 0 < N) ? cnt[base + 0] : 0u;
    unsigned c1 = (base + 1 < N) ? cnt[base + 1] : 0u;
    unsigned c2 = (base + 2 < N) ? cnt[base + 2] : 0u;
    unsigned c3 = (base + 3 < N) ? cnt[base + 3] : 0u;
    unsigned s = c0 + c1 + c2 + c3;
    sc[threadIdx.x] = s;
    __syncthreads();
    for (int off = 1; off < 256; off <<= 1) {
        unsigned t = (threadIdx.x >= (unsigned)off) ? sc[threadIdx.x - off] : 0u;
        __syncthreads();
        sc[threadIdx.x] += t;
        __syncthreads();
    }
    unsigned excl = sc[threadIdx.x] - s;
    if (base + 0 < N) part[base + 0] = excl;
    if (base + 1 < N) part[base + 1] = excl + c0;
    if (base + 2 < N) part[base + 2] = excl + c0 + c1;
    if (base + 3 < N) part[base + 3] = excl + c0 + c1 + c2;
    if (threadIdx.x == 255) bsum[blockIdx.x] = sc[255];
}

// Scan level 2: single block, exclusive scan of the <=256 chunk totals.
__global__ __launch_bounds__(256)
void nscan2_kernel(unsigned* __restrict__ bsum, int nb) {
    __shared__ unsigned sc[256];
    unsigned v = (threadIdx.x < (unsigned)nb) ? bsum[threadIdx.x] : 0u;
    sc[threadIdx.x] = v;
    __syncthreads();
    for (int off = 1; off < 256; off <<= 1) {
        unsigned t = (threadIdx.x >= (unsigned)off) ? sc[threadIdx.x - off] : 0u;
        __syncthreads();
        sc[threadIdx.x] += t;
        __syncthreads();
    }
    if (threadIdx.x < (unsigned)nb) bsum[threadIdx.x] = sc[threadIdx.x] - v;
}

// Scan level 3: add chunk offset; produce nodeStart and nodeCur (working copy).
__global__ __launch_bounds__(256)
void nscan3_kernel(unsigned* __restrict__ part,
                   const unsigned* __restrict__ bsum,
                   unsigned* __restrict__ cur, int N) {
    const int base = (int)blockIdx.x * SCAN_B + (int)threadIdx.x * 4;
    const unsigned o = bsum[blockIdx.x];
    #pragma unroll
    for (int k = 0; k < 4; ++k) {
        if (base + k < N) {
            unsigned ns = part[base + k] + o;
            part[base + k] = ns;
            cur[base + k] = ns;
        }
    }
}

__global__ __launch_bounds__(256)
void scatter_node_kernel(const int* __restrict__ dst,
                         unsigned* __restrict__ cur,
                         unsigned* __restrict__ eid, int E) {
    const int stride = (int)gridDim.x * 256 * 4;
    for (int i = ((int)blockIdx.x * 256 + (int)threadIdx.x) * 4; i < E; i += stride) {
        if (i + 4 <= E) {
            int4 d = *reinterpret_cast<const int4*>(dst + i);
            unsigned q0 = atomicAdd(&cur[d.x], 1u);
            unsigned q1 = atomicAdd(&cur[d.y], 1u);
            unsigned q2 = atomicAdd(&cur[d.z], 1u);
            unsigned q3 = atomicAdd(&cur[d.w], 1u);
            if (q0 < (unsigned)E) eid[q0] = (unsigned)(i + 0);
            if (q1 < (unsigned)E) eid[q1] = (unsigned)(i + 1);
            if (q2 < (unsigned)E) eid[q2] = (unsigned)(i + 2);
            if (q3 < (unsigned)E) eid[q3] = (unsigned)(i + 3);
        } else {
            for (int j = i; j < E; ++j) {
                unsigned q = atomicAdd(&cur[dst[j]], 1u);
                if (q < (unsigned)E) eid[q] = (unsigned)j;
            }
        }
    }
}

// One wave per node: gather scores of its edges, register butterfly reduce,
// write AB[node] = [A(8) | B(8)] (one 64B line). No LDS, no atomics.
__global__ __launch_bounds__(256)
void node_stats_kernel(const unsigned* __restrict__ eid,
                       const unsigned* __restrict__ nodeStart,
                       const unsigned* __restrict__ nodeCnt,
                       const float* __restrict__ scores,
                       const float* __restrict__ gain,
                       const float* __restrict__ bias,
                       float* __restrict__ AB, int E) {
    const int node = (int)blockIdx.x * 4 + ((int)threadIdx.x >> 6);
    if (node >= NNODES) return;               // wave-uniform exit
    const int lane = (int)threadIdx.x & 63;
    const unsigned start = nodeStart[node];
    const int cnt = (int)nodeCnt[node];

    float v[8], w[8];
    #pragma unroll
    for (int k = 0; k < 8; ++k) { v[k] = 0.f; w[k] = 0.f; }

    for (int b0 = 0; b0 < cnt; b0 += 64) {
        int i = b0 + lane;
        if (i < cnt) {
            unsigned idx = start + (unsigned)i;
            unsigned e = (idx < (unsigned)E) ? eid[idx] : 0u;
            const float4* p =
                reinterpret_cast<const float4*>(scores + (size_t)e * NHEADS);
            float4 x0 = p[0], x1 = p[1];
            float xs[8] = {x0.x, x0.y, x0.z, x0.w, x1.x, x1.y, x1.z, x1.w};
            #pragma unroll
            for (int k = 0; k < 8; ++k) {
                v[k] += xs[k];
                w[k] += xs[k] * xs[k];
            }
        }
    }

    // 64-lane butterfly: every lane ends with full sums for all 8 heads.
    #pragma unroll
    for (int m = 1; m < 64; m <<= 1) {
        #pragma unroll
        for (int k = 0; k < 8; ++k) {
            v[k] += __shfl_xor(v[k], m);
            w[k] += __shfl_xor(w[k], m);
        }
    }

    if (lane == 0) {
        float cm = fmaxf((float)cnt, 1.0f);   // ref: sums / max(counts,1)
        float a[8], bb[8];
        #pragma unroll
        for (int h = 0; h < 8; ++h) {
            float mean = v[h] / cm;
            float var  = fmaxf(w[h] - v[h] * mean, 0.0f);   // clamped 1-pass var
            float inv  = 1.0f / fmaxf(sqrtf(var / cm), 1e-5f);
            a[h]  = gain[h] * inv;
            bb[h] = fmaf(-a[h], mean, bias[h]);
        }
        float4* po = reinterpret_cast<float4*>(AB + (size_t)node * 16);
        po[0] = float4{a[0], a[1], a[2], a[3]};
        po[1] = float4{a[4], a[5], a[6], a[7]};
        po[2] = float4{bb[0], bb[1], bb[2], bb[3]};
        po[3] = float4{bb[4], bb[5], bb[6], bb[7]};
    }
}

__global__ __launch_bounds__(256)
void edge_out_kernel(const float* __restrict__ scores,
                     const int* __restrict__ dst,
                     const float* __restrict__ AB,
                     float* __restrict__ out,
                     int num_edges) {
    int e = blockIdx.x * 256 + threadIdx.x;
    if (e >= num_edges) return;
    int d = dst[e];
    const float4* px  = reinterpret_cast<const float4*>(scores + (size_t)e * NHEADS);
    const float4* pab = reinterpret_cast<const float4*>(AB + (size_t)d * 16);
    float4 x0 = px[0], x1 = px[1];
    float4 a0 = pab[0], a1 = pab[1];
    float4 b0 = pab[2], b1 = pab[3];
    float4 o0, o1;
    o0.x = fmaf(a0.x, x0.x, b0.x);
    o0.y = fmaf(a0.y, x0.y, b0.y);
    o0.z = fmaf(a0.z, x0.z, b0.z);
    o0.w = fmaf(a0.w, x0.w, b0.w);
    o1.x = fmaf(a1.x, x1.x, b1.x);
    o1.y = fmaf(a1.y, x1.y, b1.y);
    o1.z = fmaf(a1.z, x1.z, b1.z);
    o1.w = fmaf(a1.w, x1.w, b1.w);
    float4* po = reinterpret_cast<float4*>(out + (size_t)e * NHEADS);
    po[0] = o0;
    po[1] = o1;
}

// ---- global-atomic fallback (only if ws implausibly small) ----------------
__global__ void edge_stats_fallback(const float* __restrict__ scores,
                                    const int* __restrict__ dst,
                                    float* __restrict__ sums,
                                    float* __restrict__ sumsq,
                                    int* __restrict__ counts,
                                    int num_edges) {
    int e = blockIdx.x * blockDim.x + threadIdx.x;
    if (e >= num_edges) return;
    int d = dst[e];
    const float4* p = reinterpret_cast<const float4*>(scores + (size_t)e * NHEADS);
    float4 x0 = p[0], x1 = p[1];
    float* s = sums  + (size_t)d * NHEADS;
    float* q = sumsq + (size_t)d * NHEADS;
    atomicAdd(s + 0, x0.x); atomicAdd(s + 1, x0.y);
    atomicAdd(s + 2, x0.z); atomicAdd(s + 3, x0.w);
    atomicAdd(s + 4, x1.x); atomicAdd(s + 5, x1.y);
    atomicAdd(s + 6, x1.z); atomicAdd(s + 7, x1.w);
    atomicAdd(q + 0, x0.x * x0.x); atomicAdd(q + 1, x0.y * x0.y);
    atomicAdd(q + 2, x0.z * x0.z); atomicAdd(q + 3, x0.w * x0.w);
    atomicAdd(q + 4, x1.x * x1.x); atomicAdd(q + 5, x1.y * x1.y);
    atomicAdd(q + 6, x1.z * x1.z); atomicAdd(q + 7, x1.w * x1.w);
    atomicAdd(counts + d, 1);
}

__global__ void coeff_fallback(const float* __restrict__ sums,
                               const float* __restrict__ sumsq,
                               const int* __restrict__ counts,
                               const float* __restrict__ gain,
                               const float* __restrict__ bias,
                               float* __restrict__ AB, int total) {
    int i = blockIdx.x * blockDim.x + threadIdx.x;
    if (i >= total) return;
    int h = i & (NHEADS - 1);
    int node = i >> 3;
    float cm = fmaxf((float)counts[node], 1.0f);
    float s = sums[i];
    float mean = s / cm;
    float var_sum = fmaxf(sumsq[i] - s * mean, 0.0f);
    float inv = 1.0f / fmaxf(sqrtf(var_sum / cm), 1e-5f);
    float a = gain[h] * inv;
    AB[(size_t)node * 16 + h]     = a;
    AB[(size_t)node * 16 + 8 + h] = fmaf(-a, mean, bias[h]);
}
// ---------------------------------------------------------------------------

extern "C" void kernel_launch(void* const* d_in, const int* in_sizes, int n_in,
                              void* d_out, int out_size, void* d_ws, size_t ws_size,
                              hipStream_t stream) {
    const float* scores = (const float*)d_in[0];
    const float* gain   = (const float*)d_in[1];
    const float* bias   = (const float*)d_in[2];
    const int*   dst    = (const int*)d_in[3];

    const int E  = in_sizes[3];
    const int N  = NNODES;
    const int NH = N * NHEADS;
    const int B  = 256;

    // ws layout (256B-aligned):
    //   AB        : N*16 f32    6.40 MB
    //   nodeCnt   : N u32       0.40 MB
    //   nodeStart : N u32       0.40 MB
    //   nodeCur   : N u32       0.40 MB
    //   bsum      : NS1B u32    ~0
    //   eid       : E u32      12.80 MB
    // Total ~20.5 MB  (ws proven >= 75 MB by round-8 P=2 selection).
    size_t off = 0;
    float* AB = (float*)d_ws;                            off += (size_t)N * 16 * 4;
    off = (off + 255) & ~(size_t)255;
    unsigned* nodeCnt   = (unsigned*)((char*)d_ws + off); off += (size_t)N * 4;
    off = (off + 255) & ~(size_t)255;
    unsigned* nodeStart = (unsigned*)((char*)d_ws + off); off += (size_t)N * 4;
    off = (off + 255) & ~(size_t)255;
    unsigned* nodeCur   = (unsigned*)((char*)d_ws + off); off += (size_t)N * 4;
    off = (off + 255) & ~(size_t)255;
    unsigned* bsum      = (unsigned*)((char*)d_ws + off); off += (size_t)NS1B * 4;
    off = (off + 255) & ~(size_t)255;
    unsigned* eid       = (unsigned*)((char*)d_ws + off); off += (size_t)E * 4;

    if (off <= ws_size) {
        const int gridE = min((E / 4 + B - 1) / B, 2048);
        zero_kernel<<<(N + B - 1) / B, B, 0, stream>>>(nodeCnt, N);
        count_node_kernel<<<gridE, B, 0, stream>>>(dst, nodeCnt, E);
        nscan1_kernel<<<NS1B, B, 0, stream>>>(nodeCnt, nodeStart, bsum, N);
        nscan2_kernel<<<1, B, 0, stream>>>(bsum, NS1B);
        nscan3_kernel<<<NS1B, B, 0, stream>>>(nodeStart, bsum, nodeCur, N);
        scatter_node_kernel<<<gridE, B, 0, stream>>>(dst, nodeCur, eid, E);
        node_stats_kernel<<<(N + 3) / 4, B, 0, stream>>>(eid, nodeStart, nodeCnt,
                                                         scores, gain, bias, AB, E);
        edge_out_kernel<<<(E + B - 1) / B, B, 0, stream>>>(scores, dst, AB,
                                                           (float*)d_out, E);
    } else {
        float* sums  = (float*)((char*)d_ws + (size_t)N * 16 * 4);
        float* sumsq = sums + NH;
        int*   cnts  = (int*)(sumsq + NH);
        hipMemsetAsync(sums, 0,
                       (size_t)(2 * NH) * sizeof(float) + (size_t)N * sizeof(int), stream);
        int blocks_e = (E + B - 1) / B;
        edge_stats_fallback<<<blocks_e, B, 0, stream>>>(scores, dst, sums, sumsq, cnts, E);
        coeff_fallback<<<(NH + B - 1) / B, B, 0, stream>>>(sums, sumsq, cnts, gain, bias, AB, NH);
        edge_out_kernel<<<blocks_e, B, 0, stream>>>(scores, dst, AB, (float*)d_out, E);
    }
}

// Round 6
// 428.882 us; speedup vs baseline: 1.7402x; 1.7402x over previous
//
#include <hip/hip_runtime.h>

// EdgeNorm, round 10: bucket-run payload move (r8, proven) + sorted-slice
// wave-per-node stats (new) -> no LDS-atomic wall, no random 64B-line pass.
//
// Measured walls so far:
//   F1: any full random 64B-line pass (gather OR scatter) ~700 GB/s ~290us
//       (r5 gather 683 GB/s; r9 scatter WRITE_SIZE 196MB for a 12.8MB array).
//   F2: 17 scattered LDS atomics/edge ~3.4-4.2 cyc/lane-op ~310us
//       (invariant across r5 random / r8 streaming stats).
// r8's scatter is the one proven-cheap permutation: chunk-local score gather
// (100KB L1/L2 window) + ~512B contiguous run writes (~110us/pass).
//
// This round: keep count/scan/base/scatter EXACTLY as r7/r8 (proven),
// replace stats: per (part,bucket) block LDS-counting-sorts its slice's
// nidx indices (u16), then one WAVE per node: 64 lanes = 8 edges x 8 heads,
// 32B-chunk reads within the bucket-run L2 window, 3x shfl_xor butterfly,
// ONE wave-wide atomicAdd (17 lanes, contiguous nodeacc[node][20] line)
// per (node,part) -> ~0.4M wave-atomics total vs 54M lane-atomics.
//
// Pipeline per pass (P in {1,2,4,8}, smallest that fits ws):
//   count -> scan -> base -> scatter(payload+nidx) -> stats(nodeacc +=)
// then: coeff(nodeacc -> AB) -> edge_out.

#define NHEADS  8
#define KSHIFT  9
#define KNODES  512
#define NNODES  100000
#define NB      196           // ceil(100000/512)
#define CBLK    1024          // count/scatter blocks
#define CHMAX   3200          // max chunk (local edge idx fits 12 bits)
#define PARTS   4             // stats slices per bucket
#define SLMAX   6144          // max slice len (worst bucket/P=1 ~4300)
#define ACCW    20            // nodeacc row: 8 sum | 8 sumsq | count | pad

__global__ __launch_bounds__(256)
void count_kernel(const int* __restrict__ dst, unsigned* __restrict__ counts,
                  int p0, int p1, int chunk) {
    __shared__ unsigned hist[NB];
    for (int i = threadIdx.x; i < NB; i += 256) hist[i] = 0u;
    __syncthreads();
    const int blk = blockIdx.x;
    const int s0 = p0 + blk * chunk;
    const int s1 = min(s0 + chunk, p1);
    for (int i = s0 + (int)threadIdx.x * 4; i < s1; i += 256 * 4) {
        if (i + 4 <= s1) {
            int4 d = *reinterpret_cast<const int4*>(dst + i);
            atomicAdd(&hist[(unsigned)d.x >> KSHIFT], 1u);
            atomicAdd(&hist[(unsigned)d.y >> KSHIFT], 1u);
            atomicAdd(&hist[(unsigned)d.z >> KSHIFT], 1u);
            atomicAdd(&hist[(unsigned)d.w >> KSHIFT], 1u);
        } else {
            for (int j = i; j < s1; ++j)
                atomicAdd(&hist[(unsigned)dst[j] >> KSHIFT], 1u);
        }
    }
    __syncthreads();
    for (int b = threadIdx.x; b < NB; b += 256)
        counts[(size_t)b * CBLK + blk] = hist[b];
}

// One block per bucket: exclusive scan of counts[b][0..CBLK) in place.
__global__ __launch_bounds__(256)
void scan_kernel(unsigned* __restrict__ counts, unsigned* __restrict__ totals) {
    __shared__ unsigned sc[256];
    const int b = blockIdx.x;
    const size_t base = (size_t)b * CBLK + (size_t)threadIdx.x * 4;
    uint4 v = *reinterpret_cast<uint4*>(counts + base);
    unsigned s = v.x + v.y + v.z + v.w;
    sc[threadIdx.x] = s;
    __syncthreads();
    for (int off = 1; off < 256; off <<= 1) {
        unsigned t = (threadIdx.x >= (unsigned)off) ? sc[threadIdx.x - off] : 0u;
        __syncthreads();
        sc[threadIdx.x] += t;
        __syncthreads();
    }
    unsigned excl = sc[threadIdx.x] - s;
    uint4 o;
    o.x = excl;
    o.y = excl + v.x;
    o.z = o.y + v.y;
    o.w = o.z + v.z;
    *reinterpret_cast<uint4*>(counts + base) = o;
    if (threadIdx.x == 255) totals[b] = sc[255];
}

// Single block: exclusive prefix over bucket totals -> compact bucket bases.
__global__ __launch_bounds__(256)
void base_kernel(const unsigned* __restrict__ totals, unsigned* __restrict__ base) {
    __shared__ unsigned sc[256];
    unsigned v = (threadIdx.x < NB) ? totals[threadIdx.x] : 0u;
    sc[threadIdx.x] = v;
    __syncthreads();
    for (int off = 1; off < 256; off <<= 1) {
        unsigned t = (threadIdx.x >= (unsigned)off) ? sc[threadIdx.x - off] : 0u;
        __syncthreads();
        sc[threadIdx.x] += t;
        __syncthreads();
    }
    if (threadIdx.x < NB) base[threadIdx.x] = sc[threadIdx.x] - v;
}

// Local counting sort of the chunk by bucket, then coalesced payload emit.
// ord[] entry: local edge idx (12b) | node-in-bucket (9b, <<12) | bucket (<<21)
__global__ __launch_bounds__(256)
void scatter_kernel(const int* __restrict__ dst,
                    const unsigned* __restrict__ counts,
                    const unsigned* __restrict__ base,
                    const float* __restrict__ scores,
                    float* __restrict__ payload,
                    unsigned short* __restrict__ nidx,
                    int p0, int p1, int chunk, unsigned capE) {
    __shared__ unsigned hist[256];      // padded to 256 for the scan
    __shared__ unsigned pfx[NB];        // local exclusive prefix
    __shared__ unsigned lofs[NB];       // running local offsets
    __shared__ unsigned gbase[NB];      // global dest base for this block's run
    __shared__ unsigned ord[CHMAX];
    const int blk = blockIdx.x;
    const int s0 = p0 + blk * chunk;
    const int s1 = min(s0 + chunk, p1);
    const int n  = s1 - s0;

    hist[threadIdx.x] = 0u;
    __syncthreads();
    // phase 1: local histogram
    for (int i = s0 + (int)threadIdx.x * 4; i < s1; i += 256 * 4) {
        if (i + 4 <= s1) {
            int4 d = *reinterpret_cast<const int4*>(dst + i);
            atomicAdd(&hist[(unsigned)d.x >> KSHIFT], 1u);
            atomicAdd(&hist[(unsigned)d.y >> KSHIFT], 1u);
            atomicAdd(&hist[(unsigned)d.z >> KSHIFT], 1u);
            atomicAdd(&hist[(unsigned)d.w >> KSHIFT], 1u);
        } else {
            for (int j = i; j < s1; ++j)
                atomicAdd(&hist[(unsigned)dst[j] >> KSHIFT], 1u);
        }
    }
    __syncthreads();
    // phase 2: in-place inclusive scan of hist -> exclusive pfx
    unsigned myc = hist[threadIdx.x];
    for (int off = 1; off < 256; off <<= 1) {
        unsigned t = (threadIdx.x >= (unsigned)off) ? hist[threadIdx.x - off] : 0u;
        __syncthreads();
        hist[threadIdx.x] += t;
        __syncthreads();
    }
    unsigned excl = hist[threadIdx.x] - myc;
    if (threadIdx.x < NB) {
        pfx[threadIdx.x]  = excl;
        lofs[threadIdx.x] = excl;
        gbase[threadIdx.x] =
            base[threadIdx.x] + counts[(size_t)threadIdx.x * CBLK + blk];
    }
    __syncthreads();
    // phase 3: bucket-order the chunk's edge ids in LDS
    for (int i = s0 + (int)threadIdx.x; i < s1; i += 256) {
        int d = dst[i];
        unsigned b = (unsigned)d >> KSHIFT;
        unsigned pos = atomicAdd(&lofs[b], 1u);
        if (pos < (unsigned)CHMAX)          // invariant: pos < n <= CHMAX
            ord[pos] = (unsigned)(i - s0) |
                       ((unsigned)(d & (KNODES - 1)) << 12) | (b << 21);
    }
    __syncthreads();
    // phase 4: emit payload in bucket order -> contiguous runs.
    // scores gather is a permutation within the chunk's 100KB window (L2-hot).
    for (int p = (int)threadIdx.x; p < n; p += 256) {
        unsigned r = ord[p];
        int el       = (int)(r & 0xFFFu);
        unsigned nib = (r >> 12) & 0x1FFu;
        unsigned b   = r >> 21;
        unsigned gi  = gbase[b] + (unsigned)p - pfx[b];
        if (gi >= capE) continue;           // invariant: gi < pass edge count
        const float4* ps = reinterpret_cast<const float4*>(
            scores + (size_t)(s0 + el) * NHEADS);
        float4 x0 = ps[0], x1 = ps[1];
        float4* pd = reinterpret_cast<float4*>(payload + (size_t)gi * NHEADS);
        pd[0] = x0;
        pd[1] = x1;
        nidx[gi] = (unsigned short)nib;
    }
}

// Block (part,bucket): LDS counting-sort of the slice's nidx indices, then
// one WAVE per node: 64 lanes = 8 edges x 8 heads, butterfly over edge
// groups, single wave-wide atomicAdd into nodeacc[node][0..16].
__global__ __launch_bounds__(256)
void stats_kernel(const float* __restrict__ payload,
                  const unsigned short* __restrict__ nidx,
                  const unsigned* __restrict__ totals,
                  const unsigned* __restrict__ baseb,
                  float* __restrict__ nodeacc) {
    __shared__ unsigned hist[KNODES];
    __shared__ unsigned seg[KNODES + 1];
    __shared__ unsigned cur[KNODES];
    __shared__ unsigned sc[256];
    __shared__ unsigned short sidx[SLMAX];

    const int part  = blockIdx.x;
    const int b     = blockIdx.y;
    const int total = (int)totals[b];
    const int rs    = (int)baseb[b];
    const int sliceLen = (total + PARTS - 1) / PARTS;
    const int l0 = min(total, part * sliceLen);
    const int l1 = min(total, l0 + sliceLen);
    const int n  = l1 - l0;                 // uniform across block
    if (n <= 0) return;
    const int gs0 = rs + l0;                // global slice start

    const int tid = (int)threadIdx.x;
    for (int i = tid; i < KNODES; i += 256) hist[i] = 0u;
    __syncthreads();
    // pass A: histogram of node-in-bucket over the slice
    for (int i = tid; i < n; i += 256) {
        if (i >= SLMAX) break;
        unsigned k = (unsigned)nidx[gs0 + i] & (KNODES - 1);
        atomicAdd(&hist[k], 1u);
    }
    __syncthreads();
    // exclusive scan of hist[512] with 256 threads (pairwise)
    unsigned a0 = hist[2 * tid];
    unsigned a1 = hist[2 * tid + 1];
    unsigned ps = a0 + a1;
    sc[tid] = ps;
    __syncthreads();
    for (int off = 1; off < 256; off <<= 1) {
        unsigned t = (tid >= off) ? sc[tid - off] : 0u;
        __syncthreads();
        sc[tid] += t;
        __syncthreads();
    }
    unsigned pexcl = sc[tid] - ps;
    seg[2 * tid]     = pexcl;
    seg[2 * tid + 1] = pexcl + a0;
    cur[2 * tid]     = pexcl;
    cur[2 * tid + 1] = pexcl + a0;
    if (tid == 255) seg[KNODES] = sc[255];
    __syncthreads();
    // pass B: place slice-local indices in node-sorted order
    for (int i = tid; i < n; i += 256) {
        if (i >= SLMAX) break;
        unsigned k = (unsigned)nidx[gs0 + i] & (KNODES - 1);
        unsigned pos = atomicAdd(&cur[k], 1u);
        if (pos < (unsigned)SLMAX) sidx[pos] = (unsigned short)i;
    }
    __syncthreads();

    // wave-per-node register reduction
    const int wv   = tid >> 6;
    const int lane = tid & 63;
    const int grp  = lane >> 3;             // edge slot 0..7
    const int h    = lane & 7;              // head
    for (int k = wv; k < KNODES; k += 4) {
        int ss = (int)seg[k];
        int ee = (int)seg[k + 1];
        int cc = ee - ss;
        if (cc <= 0) continue;
        float v = 0.f, w = 0.f;
        for (int j = grp; j < cc; j += 8) {
            int li = (int)sidx[ss + j];
            float x = payload[(size_t)(gs0 + li) * NHEADS + h];
            v += x;
            w = fmaf(x, x, w);
        }
        v += __shfl_xor(v, 8);  w += __shfl_xor(w, 8);
        v += __shfl_xor(v, 16); w += __shfl_xor(w, 16);
        v += __shfl_xor(v, 32); w += __shfl_xor(w, 32);
        int gnode = b * KNODES + k;
        if (lane < 17 && gnode < NNODES) {
            float val = (lane < 8) ? v : ((lane < 16) ? w : (float)cc);
            atomicAdd(&nodeacc[(size_t)gnode * ACCW + lane], val);
        }
    }
}

// AB layout: per node 16 floats = one 64B line: [A(8) | B(8)].
__global__ __launch_bounds__(256)
void coeff_kernel(const float* __restrict__ nodeacc,
                  const float* __restrict__ gain,
                  const float* __restrict__ bias,
                  float* __restrict__ AB, int total) {
    int i = blockIdx.x * 256 + threadIdx.x;
    if (i >= total) return;
    int node = i >> 3, h = i & 7;
    const float* acc = nodeacc + (size_t)node * ACCW;
    float s = acc[h];
    float q = acc[8 + h];
    float c = acc[16];
    float cm   = fmaxf(c, 1.0f);                 // ref: sums / max(counts,1)
    float mean = s / cm;
    float var  = fmaxf(q - s * mean, 0.0f);      // one-pass variance, clamped
    float inv  = 1.0f / fmaxf(sqrtf(var / cm), 1e-5f);
    float a = gain[h] * inv;
    AB[(size_t)node * 16 + h]     = a;
    AB[(size_t)node * 16 + 8 + h] = fmaf(-a, mean, bias[h]);
}

__global__ __launch_bounds__(256)
void edge_out_kernel(const float* __restrict__ scores,
                     const int* __restrict__ dst,
                     const float* __restrict__ AB,
                     float* __restrict__ out,
                     int num_edges) {
    int e = blockIdx.x * 256 + threadIdx.x;
    if (e >= num_edges) return;
    int d = dst[e];
    const float4* px  = reinterpret_cast<const float4*>(scores + (size_t)e * NHEADS);
    const float4* pab = reinterpret_cast<const float4*>(AB + (size_t)d * 16);
    float4 x0 = px[0], x1 = px[1];
    float4 a0 = pab[0], a1 = pab[1];
    float4 b0 = pab[2], b1 = pab[3];
    float4 o0, o1;
    o0.x = fmaf(a0.x, x0.x, b0.x);
    o0.y = fmaf(a0.y, x0.y, b0.y);
    o0.z = fmaf(a0.z, x0.z, b0.z);
    o0.w = fmaf(a0.w, x0.w, b0.w);
    o1.x = fmaf(a1.x, x1.x, b1.x);
    o1.y = fmaf(a1.y, x1.y, b1.y);
    o1.z = fmaf(a1.z, x1.z, b1.z);
    o1.w = fmaf(a1.w, x1.w, b1.w);
    float4* po = reinterpret_cast<float4*>(out + (size_t)e * NHEADS);
    po[0] = o0;
    po[1] = o1;
}

// ---- global-atomic fallback (only if ws implausibly small) ----------------
__global__ void edge_stats_fallback(const float* __restrict__ scores,
                                    const int* __restrict__ dst,
                                    float* __restrict__ sums,
                                    float* __restrict__ sumsq,
                                    int* __restrict__ counts,
                                    int num_edges) {
    int e = blockIdx.x * blockDim.x + threadIdx.x;
    if (e >= num_edges) return;
    int d = dst[e];
    const float4* p = reinterpret_cast<const float4*>(scores + (size_t)e * NHEADS);
    float4 x0 = p[0], x1 = p[1];
    float* s = sums  + (size_t)d * NHEADS;
    float* q = sumsq + (size_t)d * NHEADS;
    atomicAdd(s + 0, x0.x); atomicAdd(s + 1, x0.y);
    atomicAdd(s + 2, x0.z); atomicAdd(s + 3, x0.w);
    atomicAdd(s + 4, x1.x); atomicAdd(s + 5, x1.y);
    atomicAdd(s + 6, x1.z); atomicAdd(s + 7, x1.w);
    atomicAdd(q + 0, x0.x * x0.x); atomicAdd(q + 1, x0.y * x0.y);
    atomicAdd(q + 2, x0.z * x0.z); atomicAdd(q + 3, x0.w * x0.w);
    atomicAdd(q + 4, x1.x * x1.x); atomicAdd(q + 5, x1.y * x1.y);
    atomicAdd(q + 6, x1.z * x1.z); atomicAdd(q + 7, x1.w * x1.w);
    atomicAdd(counts + d, 1);
}

__global__ void coeff_fallback(const float* __restrict__ sums,
                               const float* __restrict__ sumsq,
                               const int* __restrict__ counts,
                               const float* __restrict__ gain,
                               const float* __restrict__ bias,
                               float* __restrict__ AB, int total) {
    int i = blockIdx.x * blockDim.x + threadIdx.x;
    if (i >= total) return;
    int h = i & (NHEADS - 1);
    int node = i >> 3;
    float cm = fmaxf((float)counts[node], 1.0f);
    float s = sums[i];
    float mean = s / cm;
    float var_sum = fmaxf(sumsq[i] - s * mean, 0.0f);
    float inv = 1.0f / fmaxf(sqrtf(var_sum / cm), 1e-5f);
    float a = gain[h] * inv;
    AB[(size_t)node * 16 + h]     = a;
    AB[(size_t)node * 16 + 8 + h] = fmaf(-a, mean, bias[h]);
}
// ---------------------------------------------------------------------------

extern "C" void kernel_launch(void* const* d_in, const int* in_sizes, int n_in,
                              void* d_out, int out_size, void* d_ws, size_t ws_size,
                              hipStream_t stream) {
    const float* scores = (const float*)d_in[0];
    const float* gain   = (const float*)d_in[1];
    const float* bias   = (const float*)d_in[2];
    const int*   dst    = (const int*)d_in[3];

    const int E  = in_sizes[3];
    const int N  = NNODES;
    const int NH = N * NHEADS;
    const int B  = 256;

    // Fixed ws sections (256B-aligned):
    //   AB       : N*16 f32          6.40 MB
    //   counts   : NB*CBLK u32       0.80 MB
    //   totals   : NB u32   base : NB u32
    //   nodeacc  : N*ACCW f32        8.00 MB
    // Per-pass sections:
    //   payload  : passE*8 f32   (P=2: 51.2 MB)
    //   nidx     : passE u16     (P=2:  3.2 MB)
    // P=2 total ~69.7 MB (< ~75 MB proven floor from round 8's P=2 run).
    size_t off = 0;
    float* AB = (float*)d_ws;                          off += (size_t)N * 16 * 4;
    off = (off + 255) & ~(size_t)255;
    unsigned* counts = (unsigned*)((char*)d_ws + off); off += (size_t)NB * CBLK * 4;
    off = (off + 255) & ~(size_t)255;
    unsigned* totals = (unsigned*)((char*)d_ws + off); off += (size_t)NB * 4;
    off = (off + 255) & ~(size_t)255;
    unsigned* baseb  = (unsigned*)((char*)d_ws + off); off += (size_t)NB * 4;
    off = (off + 255) & ~(size_t)255;
    float* nodeacc   = (float*)((char*)d_ws + off);    off += (size_t)N * ACCW * 4;
    off = (off + 255) & ~(size_t)255;
    const size_t fixed = off;

    // Choose pass count: smallest P with chunk<=CHMAX and ws fit.
    int P = 0, chunk = 0;
    size_t payOff = 0, nixOff = 0;
    size_t passCap = 0;
    const int cand[4] = {1, 2, 4, 8};
    for (int ci = 0; ci < 4; ++ci) {
        int p = cand[ci];
        long long perPass = ((long long)E + p - 1) / p;
        long long ch = (((perPass + CBLK - 1) / CBLK) + 3) & ~3LL;
        if (ch > CHMAX) continue;
        size_t passE = (size_t)ch * CBLK;
        size_t po = fixed;
        size_t no = (po + passE * NHEADS * 4 + 255) & ~(size_t)255;
        size_t need = no + passE * 2;
        if (need <= ws_size) {
            P = p; chunk = (int)ch; payOff = po; nixOff = no; passCap = passE;
            break;
        }
    }

    if (P) {
        float* payload = (float*)((char*)d_ws + payOff);
        unsigned short* nidx = (unsigned short*)((char*)d_ws + nixOff);
        hipMemsetAsync(nodeacc, 0, (size_t)N * ACCW * 4, stream);
        for (int pass = 0; pass < P; ++pass) {
            int p0 = pass * chunk * CBLK;
            if (p0 >= E) break;
            int p1 = min(E, p0 + chunk * CBLK);
            count_kernel<<<CBLK, B, 0, stream>>>(dst, counts, p0, p1, chunk);
            scan_kernel<<<NB, B, 0, stream>>>(counts, totals);
            base_kernel<<<1, B, 0, stream>>>(totals, baseb);
            scatter_kernel<<<CBLK, B, 0, stream>>>(dst, counts, baseb, scores,
                                                   payload, nidx, p0, p1, chunk,
                                                   (unsigned)passCap);
            dim3 gs(PARTS, NB);
            stats_kernel<<<gs, B, 0, stream>>>(payload, nidx, totals, baseb,
                                               nodeacc);
        }
        coeff_kernel<<<(NH + B - 1) / B, B, 0, stream>>>(nodeacc, gain, bias, AB, NH);
        edge_out_kernel<<<(E + B - 1) / B, B, 0, stream>>>(scores, dst, AB,
                                                           (float*)d_out, E);
    } else {
        float* sums  = (float*)((char*)d_ws + (size_t)N * 16 * 4);
        float* sumsq = sums + NH;
        int*   cnts  = (int*)(sumsq + NH);
        hipMemsetAsync(sums, 0,
                       (size_t)(2 * NH) * sizeof(float) + (size_t)N * sizeof(int), stream);
        int blocks_e = (E + B - 1) / B;
        edge_stats_fallback<<<blocks_e, B, 0, stream>>>(scores, dst, sums, sumsq, cnts, E);
        coeff_fallback<<<(NH + B - 1) / B, B, 0, stream>>>(sums, sumsq, cnts, gain, bias, AB, NH);
        edge_out_kernel<<<blocks_e, B, 0, stream>>>(scores, dst, AB, (float*)d_out, E);
    }
}